// Round 9
// baseline (569.261 us; speedup 1.0000x reference)
//
#include <hip/hip_runtime.h>

#define NN 100000
#define EE 1600000
#define FD 128
#define NBK 391     // buckets of 256 nodes (dst >> 8)
#define BCAP 5120   // arena capacity per bucket (mean 4092, sigma ~64)
#define CHUNK 4096  // edges per pass1 block

typedef __attribute__((ext_vector_type(8))) short bf16x8;
typedef __attribute__((ext_vector_type(4))) float f32x4;

static __device__ __forceinline__ unsigned bfpack(float lo, float hi) {
  unsigned a = __float_as_uint(lo), b = __float_as_uint(hi);
  a = (a + 0x7FFFu + ((a >> 16) & 1u)) >> 16;
  b = (b + 0x7FFFu + ((b >> 16) & 1u)) >> 16;
  return a | (b << 16);
}
static __device__ __forceinline__ ushort bfround(float x) {
  unsigned u = __float_as_uint(x);
  u = (u + 0x7FFFu + ((u >> 16) & 1u)) >> 16;
  return (ushort)u;
}
static __device__ __forceinline__ float bflo(unsigned u) {
  return __uint_as_float(u << 16);
}
static __device__ __forceinline__ float bfhi(unsigned u) {
  return __uint_as_float(u & 0xFFFF0000u);
}

// ===== kernel A: pass1 bucket-binning (+wconv on extra blocks) =====
__global__ __launch_bounds__(256) void pass1_wconv(const int* __restrict__ src,
                                                   const int* __restrict__ dst,
                                                   unsigned* __restrict__ gcur,
                                                   unsigned* __restrict__ arena,
                                                   const float* __restrict__ W1,
                                                   const float* __restrict__ W2,
                                                   ushort* __restrict__ Wt1g,
                                                   ushort* __restrict__ Wt2g) {
  __shared__ unsigned hist[NBK + 1];
  __shared__ unsigned scan[512];
  __shared__ unsigned gpos[NBK + 1];
  __shared__ unsigned sorted[CHUNK];
  int t = threadIdx.x;

  if (blockIdx.x >= NBK) {  // ---- wconv role ----
    int i = (int)(blockIdx.x - NBK) * 256 + t;
    if (i < 128 * 128) {
      int k = i >> 7, c = i & 127;
      Wt1g[c * 128 + k] = bfround(W1[i]);
    } else {
      int j = i - 128 * 128;
      if (j < 128 * 64) {
        int k = j >> 6, c = j & 63;
        Wt2g[c * 128 + k] = bfround(W2[j]);
      }
    }
    return;
  }

  int base = blockIdx.x * CHUNK;
  hist[t] = 0;
  if (t + 256 <= NBK) hist[t + 256] = 0;
  __syncthreads();

  int dreg[16], sreg[16];
#pragma unroll
  for (int j = 0; j < 16; ++j) {
    int e = base + t + j * 256;
    if (e < EE) {
      dreg[j] = dst[e];
      sreg[j] = src[e];
      atomicAdd(&hist[dreg[j] >> 8], 1u);
    } else {
      dreg[j] = -1;
      sreg[j] = 0;
    }
  }
  __syncthreads();

  scan[t] = (t < NBK) ? hist[t] : 0;
  scan[t + 256] = (t + 256 < NBK) ? hist[t + 256] : 0;
  __syncthreads();
  for (int d = 1; d < 512; d <<= 1) {
    unsigned r0 = (t >= d) ? scan[t - d] : 0;
    unsigned r1 = ((t + 256) >= d) ? scan[t + 256 - d] : 0;
    __syncthreads();
    scan[t] += r0;
    scan[t + 256] += r1;
    __syncthreads();
  }
  unsigned c0 = (t < NBK) ? scan[t] - hist[t] : 0;
  unsigned c1 = (t + 256 < NBK) ? scan[t + 256] - hist[t + 256] : 0;
  __syncthreads();
  if (t < NBK) hist[t] = c0;
  if (t + 256 < NBK) hist[t + 256] = c1;
  __syncthreads();

#pragma unroll
  for (int j = 0; j < 16; ++j) {
    if (dreg[j] >= 0) {
      int b = dreg[j] >> 8;
      unsigned pos = atomicAdd(&hist[b], 1u);
      sorted[pos] = ((unsigned)(dreg[j] & 255) << 20) | (unsigned)sreg[j];
    }
  }
  __syncthreads();

  if (t < NBK) {
    unsigned lo = t ? scan[t - 1] : 0;
    unsigned cntb = scan[t] - lo;
    if (cntb) gpos[t] = atomicAdd(&gcur[t], cntb);
  }
  if (t + 256 < NBK) {
    unsigned lo = scan[t + 255];
    unsigned cntb = scan[t + 256] - lo;
    if (cntb) gpos[t + 256] = atomicAdd(&gcur[t + 256], cntb);
  }
  __syncthreads();

  int w = t >> 6, lane = t & 63;
  for (int b = w; b < NBK; b += 4) {
    unsigned lo = b ? scan[b - 1] : 0;
    unsigned cntb = scan[b] - lo;
    if (!cntb) continue;
    unsigned gp = gpos[b];
    if (gp >= BCAP) continue;
    unsigned lim = min(gp + cntb, (unsigned)BCAP) - gp;
    for (unsigned i = lane; i < lim; i += 64)
      arena[(size_t)b * BCAP + gp + i] = sorted[lo + i];
  }
}

// ===== shared gemm body: out_bf16[rows 64 x NCOLS] = A @ W (fp32 A) =====
template <int NCOLS>
static __device__ __forceinline__ void gemm_body_f32(const float* __restrict__ A,
                                                     const ushort* __restrict__ Wtg,
                                                     ushort* __restrict__ out, int bid,
                                                     int t, ushort* Wt, ushort* As) {
  constexpr int NCT = NCOLS / 16;
  int node0 = bid * 64;
  for (int idx = t; idx < NCOLS * 16; idx += 256) {
    int flat = idx * 8;
    int c = flat >> 7, k = flat & 127;
    uint4 v = *reinterpret_cast<const uint4*>(Wtg + flat);
    *reinterpret_cast<uint4*>(&Wt[c * 136 + k]) = v;
  }
  {
    int r = t >> 2, cq = (t & 3) * 32;
    int row = node0 + r;
    if (row >= NN) row = NN - 1;
    const float4* s = reinterpret_cast<const float4*>(A + (size_t)row * FD + cq);
    unsigned dv[16];
#pragma unroll
    for (int q = 0; q < 8; ++q) {
      float4 f = s[q];
      dv[q * 2 + 0] = bfpack(f.x, f.y);
      dv[q * 2 + 1] = bfpack(f.z, f.w);
    }
    uint4* d = reinterpret_cast<uint4*>(&As[r * 136 + cq]);
#pragma unroll
    for (int q = 0; q < 4; ++q)
      d[q] = make_uint4(dv[q * 4 + 0], dv[q * 4 + 1], dv[q * 4 + 2], dv[q * 4 + 3]);
  }
  __syncthreads();

  int w = t >> 6, l = t & 63;
  int lr = l & 15, lq = l >> 4;
  f32x4 acc[NCT];
#pragma unroll
  for (int ct = 0; ct < NCT; ++ct) acc[ct] = (f32x4)0.0f;
  const ushort* aBase = &As[(w * 16 + lr) * 136 + lq * 8];
  const ushort* bBase = &Wt[lr * 136 + lq * 8];
#pragma unroll
  for (int ks = 0; ks < 4; ++ks) {
    bf16x8 a = *reinterpret_cast<const bf16x8*>(aBase + ks * 32);
#pragma unroll
    for (int ct = 0; ct < NCT; ++ct) {
      bf16x8 b = *reinterpret_cast<const bf16x8*>(bBase + ct * 16 * 136 + ks * 32);
      acc[ct] = __builtin_amdgcn_mfma_f32_16x16x32_bf16(a, b, acc[ct], 0, 0, 0);
    }
  }
  int rowb = node0 + w * 16 + lq * 4;
#pragma unroll
  for (int ct = 0; ct < NCT; ++ct) {
#pragma unroll
    for (int r = 0; r < 4; ++r) {
      int row = rowb + r;
      if (row < NN) out[(size_t)row * NCOLS + ct * 16 + lr] = bfround(acc[ct][r]);
    }
  }
}

// ===== kernel B: pass2 counting sort (blocks < NBK) + gemm1 (rest) =====
__global__ __launch_bounds__(256) void pass2_gemm1(const unsigned* __restrict__ arena,
                                                   const unsigned* __restrict__ gcur,
                                                   int* __restrict__ nbr,
                                                   int* __restrict__ cur,
                                                   const float* __restrict__ x,
                                                   const ushort* __restrict__ Wt1g,
                                                   ushort* __restrict__ y1) {
  __shared__ __align__(16) char smem[52224];
  int t = threadIdx.x;

  if (blockIdx.x >= NBK) {  // ---- gemm1 role ----
    gemm_body_f32<128>(x, Wt1g, y1, (int)(blockIdx.x - NBK), t, (ushort*)smem,
                       (ushort*)(smem + 34816));
    return;
  }

  // ---- pass2 role ----
  unsigned* sh = (unsigned*)smem;           // 512
  unsigned* hist = sh + 512;                // 256
  unsigned* scn = hist + 256;               // 256
  unsigned* sorted = scn + 256;             // BCAP
  int b = blockIdx.x;

  unsigned v0 = (t < NBK) ? gcur[t] : 0;
  unsigned v1 = (t + 256 < NBK) ? gcur[t + 256] : 0;
  sh[t] = v0;
  sh[t + 256] = v1;
  __syncthreads();
  for (int d = 1; d < 512; d <<= 1) {
    unsigned r0 = (t >= d) ? sh[t - d] : 0;
    unsigned r1 = ((t + 256) >= d) ? sh[t + 256 - d] : 0;
    __syncthreads();
    sh[t] += r0;
    sh[t + 256] += r1;
    __syncthreads();
  }
  unsigned base = b ? sh[b - 1] : 0;
  unsigned cnt = min(sh[b] - base, (unsigned)BCAP);
  const unsigned* run = arena + (size_t)b * BCAP;

  hist[t] = 0;
  __syncthreads();
  for (unsigned i = t; i < cnt; i += 256) atomicAdd(&hist[run[i] >> 20], 1u);
  __syncthreads();
  scn[t] = hist[t];
  __syncthreads();
  for (int d = 1; d < 256; d <<= 1) {
    unsigned r = (t >= d) ? scn[t - d] : 0;
    __syncthreads();
    scn[t] += r;
    __syncthreads();
  }
  unsigned excl = scn[t] - hist[t];
  __syncthreads();
  hist[t] = excl;
  __syncthreads();
  for (unsigned i = t; i < cnt; i += 256) {
    unsigned v = run[i];
    unsigned pos = atomicAdd(&hist[v >> 20], 1u);
    sorted[pos] = v & 0xFFFFFu;
  }
  __syncthreads();
  for (unsigned i = t; i < cnt; i += 256) nbr[base + i] = (int)sorted[i];
  int node = b * 256 + t;
  if (node < NN) cur[node] = (int)(base + scn[t]);
}

// ===== MFMA GEMM (standalone, bf16 A): y2 = h1 @ W2 =====
__global__ __launch_bounds__(256) void mfma_gemm64(const ushort* __restrict__ A,
                                                   const ushort* __restrict__ Wtg,
                                                   ushort* __restrict__ out) {
  __shared__ ushort Wt[64 * 136];
  __shared__ ushort As[64 * 136];
  int t = threadIdx.x;
  int node0 = blockIdx.x * 64;

  for (int idx = t; idx < 64 * 16; idx += 256) {
    int flat = idx * 8;
    int c = flat >> 7, k = flat & 127;
    uint4 v = *reinterpret_cast<const uint4*>(Wtg + flat);
    *reinterpret_cast<uint4*>(&Wt[c * 136 + k]) = v;
  }
  {
    int r = t >> 2, cq = (t & 3) * 32;
    int row = node0 + r;
    if (row >= NN) row = NN - 1;
    const uint4* s = reinterpret_cast<const uint4*>(A + (size_t)row * FD + cq);
    uint4* d = reinterpret_cast<uint4*>(&As[r * 136 + cq]);
    d[0] = s[0]; d[1] = s[1]; d[2] = s[2]; d[3] = s[3];
  }
  __syncthreads();

  int w = t >> 6, l = t & 63;
  int lr = l & 15, lq = l >> 4;
  f32x4 acc[4];
#pragma unroll
  for (int ct = 0; ct < 4; ++ct) acc[ct] = (f32x4)0.0f;
  const ushort* aBase = &As[(w * 16 + lr) * 136 + lq * 8];
  const ushort* bBase = &Wt[lr * 136 + lq * 8];
#pragma unroll
  for (int ks = 0; ks < 4; ++ks) {
    bf16x8 a = *reinterpret_cast<const bf16x8*>(aBase + ks * 32);
#pragma unroll
    for (int ct = 0; ct < 4; ++ct) {
      bf16x8 b = *reinterpret_cast<const bf16x8*>(bBase + ct * 16 * 136 + ks * 32);
      acc[ct] = __builtin_amdgcn_mfma_f32_16x16x32_bf16(a, b, acc[ct], 0, 0, 0);
    }
  }
  int rowb = node0 + w * 16 + lq * 4;
#pragma unroll
  for (int ct = 0; ct < 4; ++ct) {
#pragma unroll
    for (int r = 0; r < 4; ++r) {
      int row = rowb + r;
      if (row < NN) out[(size_t)row * 64 + ct * 16 + lr] = bfround(acc[ct][r]);
    }
  }
}

// ===== XCD-sliced gather D=128 =====
// slice = blockIdx&7 -> pinned to one XCD (round-robin dispatch); each XCD's
// working set = 1/8 of the y1 table = 3.2 MB < 4 MB L2. Lanes: 8 edge-groups
// x 8 u32-slots; butterfly-reduce over groups. nbr/out accessed nontemporally
// so the table slice stays L2-resident.
__global__ __launch_bounds__(256) void gather128_sliced(const unsigned* __restrict__ Y,
                                                        const int* __restrict__ cur,
                                                        const int* __restrict__ nbr,
                                                        const float* __restrict__ bias,
                                                        unsigned* __restrict__ outp) {
  int slice = blockIdx.x & 7;
  int node = (blockIdx.x >> 3) * 4 + (threadIdx.x >> 6);
  if (node >= NN) return;
  int lane = threadIdx.x & 63;
  int eg = lane >> 3;        // edge group 0..7
  int sl = lane & 7;         // u32 slot within slice
  int base = slice * 8 + sl; // u32 index within 64-u32 row

  int s0 = __builtin_amdgcn_readfirstlane(node ? cur[node - 1] : 0);
  int s1 = __builtin_amdgcn_readfirstlane(cur[node]);
  float inv = 1.0f / (float)(s1 - s0 + 1);

  float ax = 0.f, ay = 0.f;
  int j = s0;
  for (; j + 16 <= s1; j += 16) {
    int n0 = __builtin_nontemporal_load(nbr + j + eg);
    int n1 = __builtin_nontemporal_load(nbr + j + 8 + eg);
    unsigned v0 = Y[(size_t)n0 * 64 + base];
    unsigned v1 = Y[(size_t)n1 * 64 + base];
    ax += bflo(v0) + bflo(v1);
    ay += bfhi(v0) + bfhi(v1);
  }
  for (; j + 8 <= s1; j += 8) {
    int n0 = __builtin_nontemporal_load(nbr + j + eg);
    unsigned v0 = Y[(size_t)n0 * 64 + base];
    ax += bflo(v0);
    ay += bfhi(v0);
  }
  int rem = s1 - j;
  if (eg < rem) {
    int n0 = __builtin_nontemporal_load(nbr + j + eg);
    unsigned v0 = Y[(size_t)n0 * 64 + base];
    ax += bflo(v0);
    ay += bfhi(v0);
  }
  // reduce across the 8 edge-groups (lanes with equal sl)
  ax += __shfl_xor(ax, 8);
  ay += __shfl_xor(ay, 8);
  ax += __shfl_xor(ax, 16);
  ay += __shfl_xor(ay, 16);
  ax += __shfl_xor(ax, 32);
  ay += __shfl_xor(ay, 32);

  if (eg == 0) {
    unsigned sv = Y[(size_t)node * 64 + base];
    float2 bv = reinterpret_cast<const float2*>(bias)[base];
    float rx = fmaxf((ax + bflo(sv)) * inv + bv.x, 0.f);
    float ry = fmaxf((ay + bfhi(sv)) * inv + bv.y, 0.f);
    __builtin_nontemporal_store(bfpack(rx, ry), outp + (size_t)node * 64 + base);
  }
}

// ===== XCD-sliced gather D=64 (4 slices; XCD x caches slice x&3) =====
__global__ __launch_bounds__(256) void gather64_sliced(const unsigned* __restrict__ Y,
                                                       const int* __restrict__ cur,
                                                       const int* __restrict__ nbr,
                                                       const float* __restrict__ bias,
                                                       float* __restrict__ out) {
  int slice = blockIdx.x & 3;
  int node = (blockIdx.x >> 2) * 4 + (threadIdx.x >> 6);
  if (node >= NN) return;
  int lane = threadIdx.x & 63;
  int eg = lane >> 3;
  int sl = lane & 7;
  int base = slice * 8 + sl;  // u32 index within 32-u32 row

  int s0 = __builtin_amdgcn_readfirstlane(node ? cur[node - 1] : 0);
  int s1 = __builtin_amdgcn_readfirstlane(cur[node]);
  float inv = 1.0f / (float)(s1 - s0 + 1);

  float ax = 0.f, ay = 0.f;
  int j = s0;
  for (; j + 16 <= s1; j += 16) {
    int n0 = __builtin_nontemporal_load(nbr + j + eg);
    int n1 = __builtin_nontemporal_load(nbr + j + 8 + eg);
    unsigned v0 = Y[(size_t)n0 * 32 + base];
    unsigned v1 = Y[(size_t)n1 * 32 + base];
    ax += bflo(v0) + bflo(v1);
    ay += bfhi(v0) + bfhi(v1);
  }
  for (; j + 8 <= s1; j += 8) {
    int n0 = __builtin_nontemporal_load(nbr + j + eg);
    unsigned v0 = Y[(size_t)n0 * 32 + base];
    ax += bflo(v0);
    ay += bfhi(v0);
  }
  int rem = s1 - j;
  if (eg < rem) {
    int n0 = __builtin_nontemporal_load(nbr + j + eg);
    unsigned v0 = Y[(size_t)n0 * 32 + base];
    ax += bflo(v0);
    ay += bfhi(v0);
  }
  ax += __shfl_xor(ax, 8);
  ay += __shfl_xor(ay, 8);
  ax += __shfl_xor(ax, 16);
  ay += __shfl_xor(ay, 16);
  ax += __shfl_xor(ax, 32);
  ay += __shfl_xor(ay, 32);

  if (eg == 0) {
    unsigned sv = Y[(size_t)node * 32 + base];
    float2 bv = reinterpret_cast<const float2*>(bias)[base];
    union { float2 f; unsigned long long u; } cvt;
    cvt.f.x = (ax + bflo(sv)) * inv + bv.x;
    cvt.f.y = (ay + bfhi(sv)) * inv + bv.y;
    __builtin_nontemporal_store(
        cvt.u, reinterpret_cast<unsigned long long*>(out + (size_t)node * 64 + base * 2));
  }
}

extern "C" void kernel_launch(void* const* d_in, const int* in_sizes, int n_in,
                              void* d_out, int out_size, void* d_ws, size_t ws_size,
                              hipStream_t stream) {
  const float* x  = (const float*)d_in[0];
  const int* src  = (const int*)d_in[1];
  const int* dst  = (const int*)d_in[2];
  const float* W1 = (const float*)d_in[3];
  const float* b1 = (const float*)d_in[4];
  const float* W2 = (const float*)d_in[5];
  const float* b2 = (const float*)d_in[6];
  float* out = (float*)d_out;

  char* ws = (char*)d_ws;
  ushort*   Wt1g  = (ushort*)(ws + 0);          //    32,768
  ushort*   Wt2g  = (ushort*)(ws + 32768);      //    16,384
  unsigned* gcur  = (unsigned*)(ws + 49152);    //     1,664
  int*      cur   = (int*)(ws + 53248);         //   400,000
  int*      nbr   = (int*)(ws + 453248);        // 6,400,000
  unsigned* arena = (unsigned*)(ws + 6853248);  // 8,007,680
  ushort*   y1    = (ushort*)(ws + 14860928);   // 25,600,000
  ushort*   h1    = (ushort*)(ws + 40460928);   // 25,600,000
  ushort*   y2    = (ushort*)(ws + 66060928);   // 12,800,000 -> ~79 MB total

  const int gemmBlocks = (NN + 63) / 64;  // 1563
  const int g128Blocks = (NN / 4) * 8;    // 200000 (slice fastest)
  const int g64Blocks  = (NN / 4) * 4;    // 100000

  // 1) zero bucket cursors
  hipMemsetAsync(gcur, 0, NBK * sizeof(unsigned), stream);
  // 2) bucket-bin edges (+ weight transpose/convert on extra blocks)
  pass1_wconv<<<NBK + 96, 256, 0, stream>>>(src, dst, gcur, arena, W1, W2, Wt1g, Wt2g);
  // 3) per-bucket sort -> CSR (+ layer-1 GEMM on extra blocks)
  pass2_gemm1<<<NBK + gemmBlocks, 256, 0, stream>>>(arena, gcur, nbr, cur, x, Wt1g, y1);
  // 4) XCD-sliced gather/normalize/ReLU layer 1 -> h1 (bf16)
  gather128_sliced<<<g128Blocks, 256, 0, stream>>>((const unsigned*)y1, cur, nbr, b1,
                                                   (unsigned*)h1);
  // 5) layer-2 GEMM: y2 = h1 @ W2 (bf16)
  mfma_gemm64<<<gemmBlocks, 256, 0, stream>>>(h1, Wt2g, y2);
  // 6) XCD-sliced final gather/normalize + bias -> out (fp32)
  gather64_sliced<<<g64Blocks, 256, 0, stream>>>((const unsigned*)y2, cur, nbr, b2, out);
}

// Round 10
// 184.838 us; speedup vs baseline: 3.0798x; 3.0798x over previous
//
#include <hip/hip_runtime.h>

#define NN 100000
#define EE 1600000
#define FD 128
#define NBK 391     // buckets of 256 nodes (dst >> 8)
#define BCAP 5120   // arena capacity per bucket (mean 4092, sigma ~64)
#define CHUNK 4096  // edges per pass1 block

typedef __attribute__((ext_vector_type(8))) short bf16x8;
typedef __attribute__((ext_vector_type(4))) float f32x4;

static __device__ __forceinline__ unsigned bfpack(float lo, float hi) {
  unsigned a = __float_as_uint(lo), b = __float_as_uint(hi);
  a = (a + 0x7FFFu + ((a >> 16) & 1u)) >> 16;
  b = (b + 0x7FFFu + ((b >> 16) & 1u)) >> 16;
  return a | (b << 16);
}
static __device__ __forceinline__ ushort bfround(float x) {
  unsigned u = __float_as_uint(x);
  u = (u + 0x7FFFu + ((u >> 16) & 1u)) >> 16;
  return (ushort)u;
}
static __device__ __forceinline__ float bflo(unsigned u) {
  return __uint_as_float(u << 16);
}
static __device__ __forceinline__ float bfhi(unsigned u) {
  return __uint_as_float(u & 0xFFFF0000u);
}

// ===== kernel A: pass1 bucket-binning (+wconv on extra blocks) =====
__global__ __launch_bounds__(256) void pass1_wconv(const int* __restrict__ src,
                                                   const int* __restrict__ dst,
                                                   unsigned* __restrict__ gcur,
                                                   unsigned* __restrict__ arena,
                                                   const float* __restrict__ W1,
                                                   const float* __restrict__ W2,
                                                   ushort* __restrict__ Wt1g,
                                                   ushort* __restrict__ Wt2g) {
  __shared__ unsigned hist[NBK + 1];
  __shared__ unsigned scan[512];
  __shared__ unsigned gpos[NBK + 1];
  __shared__ unsigned sorted[CHUNK];
  int t = threadIdx.x;

  if (blockIdx.x >= NBK) {  // ---- wconv role ----
    int i = (int)(blockIdx.x - NBK) * 256 + t;
    if (i < 128 * 128) {
      int k = i >> 7, c = i & 127;
      Wt1g[c * 128 + k] = bfround(W1[i]);
    } else {
      int j = i - 128 * 128;
      if (j < 128 * 64) {
        int k = j >> 6, c = j & 63;
        Wt2g[c * 128 + k] = bfround(W2[j]);
      }
    }
    return;
  }

  int base = blockIdx.x * CHUNK;
  hist[t] = 0;
  if (t + 256 <= NBK) hist[t + 256] = 0;
  __syncthreads();

  int dreg[16], sreg[16];
#pragma unroll
  for (int j = 0; j < 16; ++j) {
    int e = base + t + j * 256;
    if (e < EE) {
      dreg[j] = dst[e];
      sreg[j] = src[e];
      atomicAdd(&hist[dreg[j] >> 8], 1u);
    } else {
      dreg[j] = -1;
      sreg[j] = 0;
    }
  }
  __syncthreads();

  scan[t] = (t < NBK) ? hist[t] : 0;
  scan[t + 256] = (t + 256 < NBK) ? hist[t + 256] : 0;
  __syncthreads();
  for (int d = 1; d < 512; d <<= 1) {
    unsigned r0 = (t >= d) ? scan[t - d] : 0;
    unsigned r1 = ((t + 256) >= d) ? scan[t + 256 - d] : 0;
    __syncthreads();
    scan[t] += r0;
    scan[t + 256] += r1;
    __syncthreads();
  }
  unsigned c0 = (t < NBK) ? scan[t] - hist[t] : 0;
  unsigned c1 = (t + 256 < NBK) ? scan[t + 256] - hist[t + 256] : 0;
  __syncthreads();
  if (t < NBK) hist[t] = c0;
  if (t + 256 < NBK) hist[t + 256] = c1;
  __syncthreads();

#pragma unroll
  for (int j = 0; j < 16; ++j) {
    if (dreg[j] >= 0) {
      int b = dreg[j] >> 8;
      unsigned pos = atomicAdd(&hist[b], 1u);
      sorted[pos] = ((unsigned)(dreg[j] & 255) << 20) | (unsigned)sreg[j];
    }
  }
  __syncthreads();

  if (t < NBK) {
    unsigned lo = t ? scan[t - 1] : 0;
    unsigned cntb = scan[t] - lo;
    if (cntb) gpos[t] = atomicAdd(&gcur[t], cntb);
  }
  if (t + 256 < NBK) {
    unsigned lo = scan[t + 255];
    unsigned cntb = scan[t + 256] - lo;
    if (cntb) gpos[t + 256] = atomicAdd(&gcur[t + 256], cntb);
  }
  __syncthreads();

  int w = t >> 6, lane = t & 63;
  for (int b = w; b < NBK; b += 4) {
    unsigned lo = b ? scan[b - 1] : 0;
    unsigned cntb = scan[b] - lo;
    if (!cntb) continue;
    unsigned gp = gpos[b];
    if (gp >= BCAP) continue;
    unsigned lim = min(gp + cntb, (unsigned)BCAP) - gp;
    for (unsigned i = lane; i < lim; i += 64)
      arena[(size_t)b * BCAP + gp + i] = sorted[lo + i];
  }
}

// ===== shared gemm body: out_bf16[rows 64 x NCOLS] = A @ W (fp32 A) =====
template <int NCOLS>
static __device__ __forceinline__ void gemm_body_f32(const float* __restrict__ A,
                                                     const ushort* __restrict__ Wtg,
                                                     ushort* __restrict__ out, int bid,
                                                     int t, ushort* Wt, ushort* As) {
  constexpr int NCT = NCOLS / 16;
  int node0 = bid * 64;
  for (int idx = t; idx < NCOLS * 16; idx += 256) {
    int flat = idx * 8;
    int c = flat >> 7, k = flat & 127;
    uint4 v = *reinterpret_cast<const uint4*>(Wtg + flat);
    *reinterpret_cast<uint4*>(&Wt[c * 136 + k]) = v;
  }
  {
    int r = t >> 2, cq = (t & 3) * 32;
    int row = node0 + r;
    if (row >= NN) row = NN - 1;
    const float4* s = reinterpret_cast<const float4*>(A + (size_t)row * FD + cq);
    unsigned dv[16];
#pragma unroll
    for (int q = 0; q < 8; ++q) {
      float4 f = s[q];
      dv[q * 2 + 0] = bfpack(f.x, f.y);
      dv[q * 2 + 1] = bfpack(f.z, f.w);
    }
    uint4* d = reinterpret_cast<uint4*>(&As[r * 136 + cq]);
#pragma unroll
    for (int q = 0; q < 4; ++q)
      d[q] = make_uint4(dv[q * 4 + 0], dv[q * 4 + 1], dv[q * 4 + 2], dv[q * 4 + 3]);
  }
  __syncthreads();

  int w = t >> 6, l = t & 63;
  int lr = l & 15, lq = l >> 4;
  f32x4 acc[NCT];
#pragma unroll
  for (int ct = 0; ct < NCT; ++ct) acc[ct] = (f32x4)0.0f;
  const ushort* aBase = &As[(w * 16 + lr) * 136 + lq * 8];
  const ushort* bBase = &Wt[lr * 136 + lq * 8];
#pragma unroll
  for (int ks = 0; ks < 4; ++ks) {
    bf16x8 a = *reinterpret_cast<const bf16x8*>(aBase + ks * 32);
#pragma unroll
    for (int ct = 0; ct < NCT; ++ct) {
      bf16x8 b = *reinterpret_cast<const bf16x8*>(bBase + ct * 16 * 136 + ks * 32);
      acc[ct] = __builtin_amdgcn_mfma_f32_16x16x32_bf16(a, b, acc[ct], 0, 0, 0);
    }
  }
  int rowb = node0 + w * 16 + lq * 4;
#pragma unroll
  for (int ct = 0; ct < NCT; ++ct) {
#pragma unroll
    for (int r = 0; r < 4; ++r) {
      int row = rowb + r;
      if (row < NN) out[(size_t)row * NCOLS + ct * 16 + lr] = bfround(acc[ct][r]);
    }
  }
}

// ===== kernel B: pass2 counting sort (blocks < NBK) + gemm1 (rest) =====
__global__ __launch_bounds__(256) void pass2_gemm1(const unsigned* __restrict__ arena,
                                                   const unsigned* __restrict__ gcur,
                                                   int* __restrict__ nbr,
                                                   int* __restrict__ cur,
                                                   const float* __restrict__ x,
                                                   const ushort* __restrict__ Wt1g,
                                                   ushort* __restrict__ y1) {
  __shared__ __align__(16) char smem[52224];
  int t = threadIdx.x;

  if (blockIdx.x >= NBK) {  // ---- gemm1 role ----
    gemm_body_f32<128>(x, Wt1g, y1, (int)(blockIdx.x - NBK), t, (ushort*)smem,
                       (ushort*)(smem + 34816));
    return;
  }

  // ---- pass2 role ----
  unsigned* sh = (unsigned*)smem;           // 512
  unsigned* hist = sh + 512;                // 256
  unsigned* scn = hist + 256;               // 256
  unsigned* sorted = scn + 256;             // BCAP
  int b = blockIdx.x;

  unsigned v0 = (t < NBK) ? gcur[t] : 0;
  unsigned v1 = (t + 256 < NBK) ? gcur[t + 256] : 0;
  sh[t] = v0;
  sh[t + 256] = v1;
  __syncthreads();
  for (int d = 1; d < 512; d <<= 1) {
    unsigned r0 = (t >= d) ? sh[t - d] : 0;
    unsigned r1 = ((t + 256) >= d) ? sh[t + 256 - d] : 0;
    __syncthreads();
    sh[t] += r0;
    sh[t + 256] += r1;
    __syncthreads();
  }
  unsigned base = b ? sh[b - 1] : 0;
  unsigned cnt = min(sh[b] - base, (unsigned)BCAP);
  const unsigned* run = arena + (size_t)b * BCAP;

  hist[t] = 0;
  __syncthreads();
  for (unsigned i = t; i < cnt; i += 256) atomicAdd(&hist[run[i] >> 20], 1u);
  __syncthreads();
  scn[t] = hist[t];
  __syncthreads();
  for (int d = 1; d < 256; d <<= 1) {
    unsigned r = (t >= d) ? scn[t - d] : 0;
    __syncthreads();
    scn[t] += r;
    __syncthreads();
  }
  unsigned excl = scn[t] - hist[t];
  __syncthreads();
  hist[t] = excl;
  __syncthreads();
  for (unsigned i = t; i < cnt; i += 256) {
    unsigned v = run[i];
    unsigned pos = atomicAdd(&hist[v >> 20], 1u);
    sorted[pos] = v & 0xFFFFFu;
  }
  __syncthreads();
  for (unsigned i = t; i < cnt; i += 256) nbr[base + i] = (int)sorted[i];
  int node = b * 256 + t;
  if (node < NN) cur[node] = (int)(base + scn[t]);
}

// ===== MFMA GEMM (standalone, bf16 A): y2 = h1 @ W2 =====
__global__ __launch_bounds__(256) void mfma_gemm64(const ushort* __restrict__ A,
                                                   const ushort* __restrict__ Wtg,
                                                   ushort* __restrict__ out) {
  __shared__ ushort Wt[64 * 136];
  __shared__ ushort As[64 * 136];
  int t = threadIdx.x;
  int node0 = blockIdx.x * 64;

  for (int idx = t; idx < 64 * 16; idx += 256) {
    int flat = idx * 8;
    int c = flat >> 7, k = flat & 127;
    uint4 v = *reinterpret_cast<const uint4*>(Wtg + flat);
    *reinterpret_cast<uint4*>(&Wt[c * 136 + k]) = v;
  }
  {
    int r = t >> 2, cq = (t & 3) * 32;
    int row = node0 + r;
    if (row >= NN) row = NN - 1;
    const uint4* s = reinterpret_cast<const uint4*>(A + (size_t)row * FD + cq);
    uint4* d = reinterpret_cast<uint4*>(&As[r * 136 + cq]);
    d[0] = s[0]; d[1] = s[1]; d[2] = s[2]; d[3] = s[3];
  }
  __syncthreads();

  int w = t >> 6, l = t & 63;
  int lr = l & 15, lq = l >> 4;
  f32x4 acc[4];
#pragma unroll
  for (int ct = 0; ct < 4; ++ct) acc[ct] = (f32x4)0.0f;
  const ushort* aBase = &As[(w * 16 + lr) * 136 + lq * 8];
  const ushort* bBase = &Wt[lr * 136 + lq * 8];
#pragma unroll
  for (int ks = 0; ks < 4; ++ks) {
    bf16x8 a = *reinterpret_cast<const bf16x8*>(aBase + ks * 32);
#pragma unroll
    for (int ct = 0; ct < 4; ++ct) {
      bf16x8 b = *reinterpret_cast<const bf16x8*>(bBase + ct * 16 * 136 + ks * 32);
      acc[ct] = __builtin_amdgcn_mfma_f32_16x16x32_bf16(a, b, acc[ct], 0, 0, 0);
    }
  }
  int rowb = node0 + w * 16 + lq * 4;
#pragma unroll
  for (int ct = 0; ct < 4; ++ct) {
#pragma unroll
    for (int r = 0; r < 4; ++r) {
      int row = rowb + r;
      if (row < NN) out[(size_t)row * 64 + ct * 16 + lr] = bfround(acc[ct][r]);
    }
  }
}

// ===== gather-aggregate D=128, 2 nodes per wave (bf16 in/out) =====
// nbr is streamed nontemporally; outputs stored nontemporally -> keep the
// randomly-accessed Y table resident in L2.
__global__ __launch_bounds__(256) void gather128_kernel(const unsigned* __restrict__ Y,
                                                        const int* __restrict__ cur,
                                                        const int* __restrict__ nbr,
                                                        const float* __restrict__ bias,
                                                        unsigned* __restrict__ outp) {
  int wv = (blockIdx.x * 256 + threadIdx.x) >> 6;
  int v0 = wv * 2;
  if (v0 >= NN) return;
  int v1 = v0 + 1;  // NN even -> always valid
  int lane = threadIdx.x & 63;
  int e0a = __builtin_amdgcn_readfirstlane(v0 ? cur[v0 - 1] : 0);
  int e1a = __builtin_amdgcn_readfirstlane(cur[v0]);
  int e1b = __builtin_amdgcn_readfirstlane(cur[v1]);
  int e0b = e1a;
  float invA = 1.0f / (float)(e1a - e0a + 1);
  float invB = 1.0f / (float)(e1b - e0b + 1);

  float ax0 = 0.f, ay0 = 0.f, ax1 = 0.f, ay1 = 0.f;
  int ja = e0a, jb = e0b;
  while (ja + 4 <= e1a && jb + 4 <= e1b) {
    unsigned a0 = Y[(size_t)__builtin_nontemporal_load(nbr + ja + 0) * 64 + lane];
    unsigned a1 = Y[(size_t)__builtin_nontemporal_load(nbr + ja + 1) * 64 + lane];
    unsigned a2 = Y[(size_t)__builtin_nontemporal_load(nbr + ja + 2) * 64 + lane];
    unsigned a3 = Y[(size_t)__builtin_nontemporal_load(nbr + ja + 3) * 64 + lane];
    unsigned b0 = Y[(size_t)__builtin_nontemporal_load(nbr + jb + 0) * 64 + lane];
    unsigned b1 = Y[(size_t)__builtin_nontemporal_load(nbr + jb + 1) * 64 + lane];
    unsigned b2 = Y[(size_t)__builtin_nontemporal_load(nbr + jb + 2) * 64 + lane];
    unsigned b3 = Y[(size_t)__builtin_nontemporal_load(nbr + jb + 3) * 64 + lane];
    ax0 += (bflo(a0) + bflo(a1)) + (bflo(a2) + bflo(a3));
    ay0 += (bfhi(a0) + bfhi(a1)) + (bfhi(a2) + bfhi(a3));
    ax1 += (bflo(b0) + bflo(b1)) + (bflo(b2) + bflo(b3));
    ay1 += (bfhi(b0) + bfhi(b1)) + (bfhi(b2) + bfhi(b3));
    ja += 4;
    jb += 4;
  }
  for (; ja + 4 <= e1a; ja += 4) {
    unsigned a0 = Y[(size_t)__builtin_nontemporal_load(nbr + ja + 0) * 64 + lane];
    unsigned a1 = Y[(size_t)__builtin_nontemporal_load(nbr + ja + 1) * 64 + lane];
    unsigned a2 = Y[(size_t)__builtin_nontemporal_load(nbr + ja + 2) * 64 + lane];
    unsigned a3 = Y[(size_t)__builtin_nontemporal_load(nbr + ja + 3) * 64 + lane];
    ax0 += (bflo(a0) + bflo(a1)) + (bflo(a2) + bflo(a3));
    ay0 += (bfhi(a0) + bfhi(a1)) + (bfhi(a2) + bfhi(a3));
  }
  for (; jb + 4 <= e1b; jb += 4) {
    unsigned b0 = Y[(size_t)__builtin_nontemporal_load(nbr + jb + 0) * 64 + lane];
    unsigned b1 = Y[(size_t)__builtin_nontemporal_load(nbr + jb + 1) * 64 + lane];
    unsigned b2 = Y[(size_t)__builtin_nontemporal_load(nbr + jb + 2) * 64 + lane];
    unsigned b3 = Y[(size_t)__builtin_nontemporal_load(nbr + jb + 3) * 64 + lane];
    ax1 += (bflo(b0) + bflo(b1)) + (bflo(b2) + bflo(b3));
    ay1 += (bfhi(b0) + bfhi(b1)) + (bfhi(b2) + bfhi(b3));
  }
  for (; ja < e1a; ++ja) {
    unsigned a = Y[(size_t)__builtin_nontemporal_load(nbr + ja) * 64 + lane];
    ax0 += bflo(a);
    ay0 += bfhi(a);
  }
  for (; jb < e1b; ++jb) {
    unsigned b = Y[(size_t)__builtin_nontemporal_load(nbr + jb) * 64 + lane];
    ax1 += bflo(b);
    ay1 += bfhi(b);
  }
  unsigned sv0 = Y[(size_t)v0 * 64 + lane];
  unsigned sv1 = Y[(size_t)v1 * 64 + lane];
  float2 bv = reinterpret_cast<const float2*>(bias)[lane];
  float rx0 = fmaxf((ax0 + bflo(sv0)) * invA + bv.x, 0.f);
  float ry0 = fmaxf((ay0 + bfhi(sv0)) * invA + bv.y, 0.f);
  float rx1 = fmaxf((ax1 + bflo(sv1)) * invB + bv.x, 0.f);
  float ry1 = fmaxf((ay1 + bfhi(sv1)) * invB + bv.y, 0.f);
  __builtin_nontemporal_store(bfpack(rx0, ry0), outp + (size_t)v0 * 64 + lane);
  __builtin_nontemporal_store(bfpack(rx1, ry1), outp + (size_t)v1 * 64 + lane);
}

// ===== gather-aggregate D=64, 2 nodes per wave (bf16 in, fp32 out) =====
__global__ __launch_bounds__(256) void gather64_kernel(const ushort* __restrict__ Y,
                                                       const int* __restrict__ cur,
                                                       const int* __restrict__ nbr,
                                                       const float* __restrict__ bias,
                                                       float* __restrict__ out) {
  int wv = (blockIdx.x * 256 + threadIdx.x) >> 6;
  int v0 = wv * 2;
  if (v0 >= NN) return;
  int v1 = v0 + 1;
  int lane = threadIdx.x & 63;
  int e0a = __builtin_amdgcn_readfirstlane(v0 ? cur[v0 - 1] : 0);
  int e1a = __builtin_amdgcn_readfirstlane(cur[v0]);
  int e1b = __builtin_amdgcn_readfirstlane(cur[v1]);
  int e0b = e1a;
  float invA = 1.0f / (float)(e1a - e0a + 1);
  float invB = 1.0f / (float)(e1b - e0b + 1);

  float s0 = 0.f, s1 = 0.f;
  int ja = e0a, jb = e0b;
  while (ja + 4 <= e1a && jb + 4 <= e1b) {
    float a0 = __uint_as_float((unsigned)Y[(size_t)__builtin_nontemporal_load(nbr + ja + 0) * 64 + lane] << 16);
    float a1 = __uint_as_float((unsigned)Y[(size_t)__builtin_nontemporal_load(nbr + ja + 1) * 64 + lane] << 16);
    float a2 = __uint_as_float((unsigned)Y[(size_t)__builtin_nontemporal_load(nbr + ja + 2) * 64 + lane] << 16);
    float a3 = __uint_as_float((unsigned)Y[(size_t)__builtin_nontemporal_load(nbr + ja + 3) * 64 + lane] << 16);
    float b0 = __uint_as_float((unsigned)Y[(size_t)__builtin_nontemporal_load(nbr + jb + 0) * 64 + lane] << 16);
    float b1 = __uint_as_float((unsigned)Y[(size_t)__builtin_nontemporal_load(nbr + jb + 1) * 64 + lane] << 16);
    float b2 = __uint_as_float((unsigned)Y[(size_t)__builtin_nontemporal_load(nbr + jb + 2) * 64 + lane] << 16);
    float b3 = __uint_as_float((unsigned)Y[(size_t)__builtin_nontemporal_load(nbr + jb + 3) * 64 + lane] << 16);
    s0 += (a0 + a1) + (a2 + a3);
    s1 += (b0 + b1) + (b2 + b3);
    ja += 4;
    jb += 4;
  }
  for (; ja + 4 <= e1a; ja += 4) {
    float a0 = __uint_as_float((unsigned)Y[(size_t)__builtin_nontemporal_load(nbr + ja + 0) * 64 + lane] << 16);
    float a1 = __uint_as_float((unsigned)Y[(size_t)__builtin_nontemporal_load(nbr + ja + 1) * 64 + lane] << 16);
    float a2 = __uint_as_float((unsigned)Y[(size_t)__builtin_nontemporal_load(nbr + ja + 2) * 64 + lane] << 16);
    float a3 = __uint_as_float((unsigned)Y[(size_t)__builtin_nontemporal_load(nbr + ja + 3) * 64 + lane] << 16);
    s0 += (a0 + a1) + (a2 + a3);
  }
  for (; jb + 4 <= e1b; jb += 4) {
    float b0 = __uint_as_float((unsigned)Y[(size_t)__builtin_nontemporal_load(nbr + jb + 0) * 64 + lane] << 16);
    float b1 = __uint_as_float((unsigned)Y[(size_t)__builtin_nontemporal_load(nbr + jb + 1) * 64 + lane] << 16);
    float b2 = __uint_as_float((unsigned)Y[(size_t)__builtin_nontemporal_load(nbr + jb + 2) * 64 + lane] << 16);
    float b3 = __uint_as_float((unsigned)Y[(size_t)__builtin_nontemporal_load(nbr + jb + 3) * 64 + lane] << 16);
    s1 += (b0 + b1) + (b2 + b3);
  }
  for (; ja < e1a; ++ja)
    s0 += __uint_as_float((unsigned)Y[(size_t)__builtin_nontemporal_load(nbr + ja) * 64 + lane] << 16);
  for (; jb < e1b; ++jb)
    s1 += __uint_as_float((unsigned)Y[(size_t)__builtin_nontemporal_load(nbr + jb) * 64 + lane] << 16);

  float self0 = __uint_as_float((unsigned)Y[(size_t)v0 * 64 + lane] << 16);
  float self1 = __uint_as_float((unsigned)Y[(size_t)v1 * 64 + lane] << 16);
  float bvv = bias[lane];
  __builtin_nontemporal_store((s0 + self0) * invA + bvv, out + (size_t)v0 * 64 + lane);
  __builtin_nontemporal_store((s1 + self1) * invB + bvv, out + (size_t)v1 * 64 + lane);
}

extern "C" void kernel_launch(void* const* d_in, const int* in_sizes, int n_in,
                              void* d_out, int out_size, void* d_ws, size_t ws_size,
                              hipStream_t stream) {
  const float* x  = (const float*)d_in[0];
  const int* src  = (const int*)d_in[1];
  const int* dst  = (const int*)d_in[2];
  const float* W1 = (const float*)d_in[3];
  const float* b1 = (const float*)d_in[4];
  const float* W2 = (const float*)d_in[5];
  const float* b2 = (const float*)d_in[6];
  float* out = (float*)d_out;

  char* ws = (char*)d_ws;
  ushort*   Wt1g  = (ushort*)(ws + 0);          //    32,768
  ushort*   Wt2g  = (ushort*)(ws + 32768);      //    16,384
  unsigned* gcur  = (unsigned*)(ws + 49152);    //     1,664
  int*      cur   = (int*)(ws + 53248);         //   400,000
  int*      nbr   = (int*)(ws + 453248);        // 6,400,000
  unsigned* arena = (unsigned*)(ws + 6853248);  // 8,007,680
  ushort*   y1    = (ushort*)(ws + 14860928);   // 25,600,000
  ushort*   h1    = (ushort*)(ws + 40460928);   // 25,600,000
  ushort*   y2    = (ushort*)(ws + 66060928);   // 12,800,000 -> ~79 MB total

  const int gemmBlocks = (NN + 63) / 64;    // 1563
  const int gathBlocks = (NN / 2 + 3) / 4;  // 12500

  // 1) zero bucket cursors
  hipMemsetAsync(gcur, 0, NBK * sizeof(unsigned), stream);
  // 2) bucket-bin edges (+ weight transpose/convert on extra blocks)
  pass1_wconv<<<NBK + 96, 256, 0, stream>>>(src, dst, gcur, arena, W1, W2, Wt1g, Wt2g);
  // 3) per-bucket sort -> CSR (+ layer-1 GEMM on extra blocks)
  pass2_gemm1<<<NBK + gemmBlocks, 256, 0, stream>>>(arena, gcur, nbr, cur, x, Wt1g, y1);
  // 4) gather/normalize/ReLU layer 1 -> h1 (bf16)   [high-occupancy, no LDS]
  gather128_kernel<<<gathBlocks, 256, 0, stream>>>((const unsigned*)y1, cur, nbr, b1,
                                                   (unsigned*)h1);
  // 5) layer-2 GEMM: y2 = h1 @ W2 (bf16)
  mfma_gemm64<<<gemmBlocks, 256, 0, stream>>>(h1, Wt2g, y2);
  // 6) final gather/normalize + bias -> out (fp32)
  gather64_kernel<<<gathBlocks, 256, 0, stream>>>(y2, cur, nbr, b2, out);
}